// Round 3
// baseline (431.030 us; speedup 1.0000x reference)
//
#include <hip/hip_runtime.h>
#include <math.h>

#define T_DIM  1024
#define B_DIM  8
#define IN_D   512
#define NROWS  (T_DIM * B_DIM)      // 8192
#define EPSF   1e-8f
#define LOG_EPS (-18.4206807f)      // logf(1e-8)

#define CHUNK  16
#define NCHUNK (T_DIM / CHUNK)      // 64
#define SEG    16
#define NSEG   (T_DIM / SEG)        // 64

#define NBLK   512u                 // fused grid size (2 blocks/CU on 256 CUs)

typedef float vfloat4 __attribute__((ext_vector_type(4)));

// ---- workspace layout (floats) ----
#define OFF_WT   0                                  // 512*192      = 98304
#define OFF_V    (OFF_WT + IN_D * 192)
#define OFF_K    (OFF_V  + NROWS * 64)
#define OFF_Z    (OFF_K  + NROWS * 64)
#define OFF_SEG  (OFF_Z  + NROWS * 64)              // 64*512 segment sums (atomic)
#define OFF_TOT  (OFF_SEG + NSEG * B_DIM * 64)
#define OFF_P    (OFF_TOT + B_DIM * 64)             // 64*8*4096 = 2097152
#define OFF_WB   (OFF_P + NCHUNK * B_DIM * 4096)    // 512*1024  = 524288 (w tiles)
#define OFF_BAR  (OFF_WB + 524288)                  // 16 uints (barrier counters)

#define FMA4(A, W, C) \
    (C).x = fmaf((A), (W).x, (C).x); (C).y = fmaf((A), (W).y, (C).y); \
    (C).z = fmaf((A), (W).z, (C).z); (C).w = fmaf((A), (W).w, (C).w);

// Grid-wide barrier. Safe because __launch_bounds__(256,2) + 56KB LDS makes all
// 512 blocks co-resident (2/CU). Relaxed polling (no per-poll L2 invalidate);
// the exit __threadfence() is the agent-scope acquire that invalidates the
// per-XCD L2 so cross-XCD producer data (written back by the pre-arrive
// __threadfence release) is visible.
__device__ __forceinline__ void gridbar(unsigned* bar, int slot) {
    __threadfence();                 // release: write back dirty L2 lines
    __syncthreads();
    if (threadIdx.x == 0) {
        atomicAdd(&bar[slot], 1u);   // device-scope arrive
        while (__hip_atomic_load(&bar[slot], __ATOMIC_RELAXED,
                                 __HIP_MEMORY_SCOPE_AGENT) < NBLK)
            __builtin_amdgcn_s_sleep(2);
        __threadfence();             // acquire: invalidate L1 + XCD L2
    }
    __syncthreads();
}

// kPre: concat+transpose weights -> Wt[i][c]; zero seg (atomic targets) + barrier slots.
__global__ void kpre(const float* __restrict__ Wv, const float* __restrict__ Wk,
                     const float* __restrict__ Wa, float* __restrict__ Wt,
                     float* __restrict__ seg, unsigned* __restrict__ bar) {
    int idx = blockIdx.x * 256 + threadIdx.x;       // < 98304
    if (idx < NSEG * 512) seg[idx] = 0.f;
    if (idx < 16) bar[idx] = 0u;
    int i = idx / 192, c = idx % 192;
    float v;
    if (c < 64)       v = Wv[c * IN_D + i];
    else if (c < 128) v = Wk[(c - 64) * IN_D + i];
    else              v = Wa[(c - 128) * IN_D + i];
    Wt[i * 192 + c] = v;
}

// Fused pipeline: P1 proj (blocks<256) | P2 partials+w | P3 chunk prefix (blocks<128) | P4 main.
__global__ __launch_bounds__(256, 2) void kfused(
        const float* __restrict__ x, const float* __restrict__ Wt,
        const float* __restrict__ bv, const float* __restrict__ bk, const float* __restrict__ ba,
        float* __restrict__ V, float* __restrict__ Kb, float* __restrict__ Zb,
        float* __restrict__ seg, float* __restrict__ P, float* __restrict__ Wb,
        float* __restrict__ S, unsigned* __restrict__ bar) {
    __shared__ float smem[14336];   // 56 KB: P1 uses all; P2/P4 use prefix slices
    const int blk = blockIdx.x;
    const int tid = threadIdx.x;

    // ---------------- P1: projections (k1 body, blocks 0..255, 32 rows each) ----------------
    if (blk < 256) {
        const int h   = tid >> 6;           // K quarter 0..3 (== wave id)
        const int sl  = h >> 1;             // slab
        const int kk0 = (h & 1) * 16;       // kk sub-range within slab
        const int t6  = tid & 63;
        const int rq  = t6 >> 4;            // 8-row group 0..3
        const int cq  = t6 & 15;            // col quad 0..15
        const int row0 = blk * 32;

        float4 acc[8][3];
#pragma unroll
        for (int j = 0; j < 8; ++j)
#pragma unroll
            for (int m = 0; m < 3; ++m) acc[j][m] = make_float4(0.f, 0.f, 0.f, 0.f);

        for (int s = 0; s < 8; ++s) {       // stage 2 slabs of 32 K per round
#pragma unroll
            for (int q = 0; q < 2; ++q) {
                int idx = tid + q * 256;            // 0..511
                int hh = idx >> 8, r = idx & 31, f = (idx >> 5) & 7;
                float4 v4 = reinterpret_cast<const float4*>(x)[((row0 + r) * IN_D + hh * 256 + s * 32 + f * 4) >> 2];
                smem[hh * 1024 + (f * 4 + 0) * 32 + r] = v4.x;
                smem[hh * 1024 + (f * 4 + 1) * 32 + r] = v4.y;
                smem[hh * 1024 + (f * 4 + 2) * 32 + r] = v4.z;
                smem[hh * 1024 + (f * 4 + 3) * 32 + r] = v4.w;
            }
#pragma unroll
            for (int q = 0; q < 12; ++q) {
                int idx = tid + q * 256;            // 0..3071
                int hh = idx / 1536;
                int rem = idx - hh * 1536;
                int kk = rem / 48;
                int f  = rem - kk * 48;
                float4 v4 = reinterpret_cast<const float4*>(Wt)[((hh * 256 + s * 32 + kk) * 192 + f * 4) >> 2];
                *reinterpret_cast<float4*>(&smem[2048 + hh * 6144 + kk * 192 + f * 4]) = v4;
            }
            __syncthreads();

#pragma unroll 4
            for (int k16 = 0; k16 < 16; ++k16) {
                const int kk = kk0 + k16;
                const float* xp = &smem[sl * 1024 + kk * 32 + rq * 8];
                float4 xv0 = *reinterpret_cast<const float4*>(xp);
                float4 xv1 = *reinterpret_cast<const float4*>(xp + 4);
                const float* wp = &smem[2048 + sl * 6144 + kk * 192 + cq * 4];
                float4 w0 = *reinterpret_cast<const float4*>(wp);
                float4 w1 = *reinterpret_cast<const float4*>(wp + 64);
                float4 w2 = *reinterpret_cast<const float4*>(wp + 128);
#pragma unroll
                for (int j = 0; j < 4; ++j) {
                    float a0 = (&xv0.x)[j];
                    float a1 = (&xv1.x)[j];
                    FMA4(a0, w0, acc[j][0]); FMA4(a0, w1, acc[j][1]); FMA4(a0, w2, acc[j][2]);
                    FMA4(a1, w0, acc[j + 4][0]); FMA4(a1, w1, acc[j + 4][1]); FMA4(a1, w2, acc[j + 4][2]);
                }
            }
            __syncthreads();
        }

        // reduce 4 K-partials (conflict-free scalar layout, 2 regions of 6144)
        float* red = smem;
        if (h == 1 || h == 3) {
            float* rg = red + (h >> 1) * 6144;
#pragma unroll
            for (int jr = 0; jr < 8; ++jr)
#pragma unroll
                for (int m = 0; m < 3; ++m)
#pragma unroll
                    for (int c = 0; c < 4; ++c)
                        rg[((jr * 3 + m) * 4 + c) * 64 + t6] = (&acc[jr][m].x)[c];
        }
        __syncthreads();
        if (h == 0 || h == 2) {
            float* rg = red + (h >> 1) * 6144;
#pragma unroll
            for (int jr = 0; jr < 8; ++jr)
#pragma unroll
                for (int m = 0; m < 3; ++m)
#pragma unroll
                    for (int c = 0; c < 4; ++c)
                        (&acc[jr][m].x)[c] += rg[((jr * 3 + m) * 4 + c) * 64 + t6];
        }
        __syncthreads();
        if (h == 2) {
#pragma unroll
            for (int jr = 0; jr < 8; ++jr)
#pragma unroll
                for (int m = 0; m < 3; ++m)
#pragma unroll
                    for (int c = 0; c < 4; ++c)
                        red[((jr * 3 + m) * 4 + c) * 64 + t6] = (&acc[jr][m].x)[c];
        }
        __syncthreads();
        if (h == 0) {
#pragma unroll
            for (int jr = 0; jr < 8; ++jr)
#pragma unroll
                for (int m = 0; m < 3; ++m)
#pragma unroll
                    for (int c = 0; c < 4; ++c)
                        (&acc[jr][m].x)[c] += red[((jr * 3 + m) * 4 + c) * 64 + t6];

            float4 bv4 = *reinterpret_cast<const float4*>(&bv[cq * 4]);
            float4 bk4 = *reinterpret_cast<const float4*>(&bk[cq * 4]);
            float4 ba4 = *reinterpret_cast<const float4*>(&ba[cq * 4]);
#pragma unroll
            for (int jr = 0; jr < 8; ++jr) {
                int row = row0 + rq * 8 + jr;
                float4 r0, r1, z2, l4;
                r0.x = acc[jr][0].x + bv4.x; r0.y = acc[jr][0].y + bv4.y;
                r0.z = acc[jr][0].z + bv4.z; r0.w = acc[jr][0].w + bv4.w;
                r1.x = acc[jr][1].x + bk4.x; r1.y = acc[jr][1].y + bk4.y;
                r1.z = acc[jr][1].z + bk4.z; r1.w = acc[jr][1].w + bk4.w;
                z2.x = acc[jr][2].x + ba4.x; z2.y = acc[jr][2].y + ba4.y;
                z2.z = acc[jr][2].z + ba4.z; z2.w = acc[jr][2].w + ba4.w;
                // log(max(sigmoid(z),eps)) = max(-log1p(exp(-z)), log(eps))
                l4.x = fmaxf(-log1pf(expf(-z2.x)), LOG_EPS);
                l4.y = fmaxf(-log1pf(expf(-z2.y)), LOG_EPS);
                l4.z = fmaxf(-log1pf(expf(-z2.z)), LOG_EPS);
                l4.w = fmaxf(-log1pf(expf(-z2.w)), LOG_EPS);
                *reinterpret_cast<float4*>(&V [row * 64 + cq * 4]) = r0;
                *reinterpret_cast<float4*>(&Kb[row * 64 + cq * 4]) = r1;
                *reinterpret_cast<float4*>(&Zb[row * 64 + cq * 4]) = l4;
                float* sp = &seg[(row >> 7) * 512 + (row & 7) * 64 + cq * 4];
                atomicAdd(sp + 0, l4.x);
                atomicAdd(sp + 1, l4.y);
                atomicAdd(sp + 2, l4.z);
                atomicAdd(sp + 3, l4.w);
            }
        }
    }

    gridbar(bar, 0);

    // ---------------- P2: phase A (w tiles) + partial outer sums (k3 body, all 512 blocks) ----------------
    {
        float* vs   = smem;             // [1024)
        float* wsh  = smem + 1024;      // [1024)
        float* gsum = smem + 2048;      // [256)
        int b = blk & 7, cch = blk >> 3;
        int dg = tid >> 4, n4 = tid & 15;
        int n = tid & 63, g = tid >> 6;
        int base = b * 64 + n;
        int il = tid >> 4, f = tid & 15;

        float4 v4 = reinterpret_cast<const float4*>(V)[((cch * CHUNK + il) * 8 + b) * 16 + f];

        float run = 0.f, total = 0.f;
#pragma unroll 8
        for (int s2 = 0; s2 < NSEG; ++s2) {
            float sv = seg[s2 * 512 + base];
            if (s2 < cch) run += sv;
            total += sv;
        }
        float invden = 1.f / (expf(total) + EPSF);

        int t0 = cch * CHUNK + g * 4;
        float l0 = Zb[(t0 + 0) * 512 + base];
        float l1 = Zb[(t0 + 1) * 512 + base];
        float l2 = Zb[(t0 + 2) * 512 + base];
        float l3 = Zb[(t0 + 3) * 512 + base];
        float k0v = Kb[(t0 + 0) * 512 + base];
        float k1v = Kb[(t0 + 1) * 512 + base];
        float k2v = Kb[(t0 + 2) * 512 + base];
        float k3v = Kb[(t0 + 3) * 512 + base];
        gsum[g * 64 + n] = l0 + l1 + l2 + l3;
        reinterpret_cast<float4*>(vs)[il * 16 + f] = v4;
        __syncthreads();
        float pre = run;
#pragma unroll
        for (int g2 = 0; g2 < 3; ++g2) if (g2 < g) pre += gsum[g2 * 64 + n];
        float c0 = pre + l0, c1 = c0 + l1, c2 = c1 + l2, c3 = c2 + l3;
        wsh[(g * 4 + 0) * 64 + n] = k0v * expf(c0) * invden;
        wsh[(g * 4 + 1) * 64 + n] = k1v * expf(c1) * invden;
        wsh[(g * 4 + 2) * 64 + n] = k2v * expf(c2) * invden;
        wsh[(g * 4 + 3) * 64 + n] = k3v * expf(c3) * invden;
        __syncthreads();

        // persist w tile for P4
        reinterpret_cast<float4*>(Wb)[(cch * 8 + b) * 256 + il * 16 + f] =
            reinterpret_cast<const float4*>(wsh)[il * 16 + f];

        float4 acc[4];
#pragma unroll
        for (int q = 0; q < 4; ++q) acc[q] = make_float4(0.f, 0.f, 0.f, 0.f);

#pragma unroll
        for (int i = 0; i < CHUNK; ++i) {
            float4 wv = reinterpret_cast<const float4*>(wsh)[i * 16 + n4];
#pragma unroll
            for (int q = 0; q < 4; ++q) {
                float vd = vs[i * 64 + dg + 16 * q];
                acc[q].x = fmaf(vd, wv.x, acc[q].x);
                acc[q].y = fmaf(vd, wv.y, acc[q].y);
                acc[q].z = fmaf(vd, wv.z, acc[q].z);
                acc[q].w = fmaf(vd, wv.w, acc[q].w);
            }
        }
        float* Pp = P + (cch * 8 + b) * 4096;
#pragma unroll
        for (int q = 0; q < 4; ++q)
            *reinterpret_cast<float4*>(Pp + (dg + 16 * q) * 64 + 4 * n4) = acc[q];
    }

    gridbar(bar, 1);

    // ---------------- P3: exclusive prefix over 64 chunks (k4 body, blocks 0..127) ----------------
    if (blk < 128) {
        int gid = blk * 256 + tid;      // < 32768
        int b = gid >> 12, dn = gid & 4095;
        float run = 0.f;
#pragma unroll
        for (int c = 0; c < NCHUNK; ++c) {
            float v = P[(c * 8 + b) * 4096 + dn];
            P[(c * 8 + b) * 4096 + dn] = run;
            run += v;
        }
    }

    gridbar(bar, 2);

    // ---------------- P4: main cumsum + streaming store (k5 body, all 512 blocks) ----------------
    {
        float* vs  = smem;              // [1024)
        float* wsh = smem + 1024;       // [1024)
        int b = blk & 7, cch = blk >> 3;
        int dg = tid >> 4, n4 = tid & 15;
        int il = tid >> 4, f = tid & 15;

        __syncthreads();    // smem was used in P2; re-cross before overwrite
        float4 v4 = reinterpret_cast<const float4*>(V)[((cch * CHUNK + il) * 8 + b) * 16 + f];
        float4 w4 = reinterpret_cast<const float4*>(Wb)[(cch * 8 + b) * 256 + il * 16 + f];
        vfloat4 acc[4];
        const float* Pp = P + (cch * 8 + b) * 4096;
#pragma unroll
        for (int q = 0; q < 4; ++q)
            acc[q] = *reinterpret_cast<const vfloat4*>(Pp + (dg + 16 * q) * 64 + 4 * n4);
        reinterpret_cast<float4*>(vs)[il * 16 + f]  = v4;
        reinterpret_cast<float4*>(wsh)[il * 16 + f] = w4;
        __syncthreads();

#pragma unroll
        for (int i = 0; i < CHUNK; ++i) {
            float4 wv = reinterpret_cast<const float4*>(wsh)[i * 16 + n4];
            int t = cch * CHUNK + i;
            float* Sb = S + (size_t)t * 32768 + b * 4096;
#pragma unroll
            for (int q = 0; q < 4; ++q) {
                float vd = vs[i * 64 + dg + 16 * q];
                acc[q].x = fmaf(vd, wv.x, acc[q].x);
                acc[q].y = fmaf(vd, wv.y, acc[q].y);
                acc[q].z = fmaf(vd, wv.z, acc[q].z);
                acc[q].w = fmaf(vd, wv.w, acc[q].w);
                __builtin_nontemporal_store(acc[q],
                    reinterpret_cast<vfloat4*>(Sb + (dg + 16 * q) * 64 + 4 * n4));
            }
        }
    }
}

extern "C" void kernel_launch(void* const* d_in, const int* in_sizes, int n_in,
                              void* d_out, int out_size, void* d_ws, size_t ws_size,
                              hipStream_t stream) {
    const float* x  = (const float*)d_in[0];
    const float* Wv = (const float*)d_in[1];
    const float* bv = (const float*)d_in[2];
    const float* Wk = (const float*)d_in[3];
    const float* bk = (const float*)d_in[4];
    const float* Wa = (const float*)d_in[5];
    const float* ba = (const float*)d_in[6];
    float* S  = (float*)d_out;
    float* ws = (float*)d_ws;

    float* Wt  = ws + OFF_WT;
    float* V   = ws + OFF_V;
    float* Kb  = ws + OFF_K;
    float* Zb  = ws + OFF_Z;
    float* seg = ws + OFF_SEG;
    float* P   = ws + OFF_P;
    float* Wb  = ws + OFF_WB;
    unsigned* bar = (unsigned*)(ws + OFF_BAR);

    kpre  <<<384, 256, 0, stream>>>(Wv, Wk, Wa, Wt, seg, bar);
    kfused<<<NBLK, 256, 0, stream>>>(x, Wt, bv, bk, ba, V, Kb, Zb, seg, P, Wb, S, bar);
}

// Round 4
// 213.343 us; speedup vs baseline: 2.0204x; 2.0204x over previous
//
#include <hip/hip_runtime.h>
#include <math.h>

#define T_DIM  1024
#define B_DIM  8
#define IN_D   512
#define NROWS  (T_DIM * B_DIM)      // 8192
#define EPSF   1e-8f

#define CHUNK  16
#define NCHUNK (T_DIM / CHUNK)      // 64
#define SEG    16
#define NSEG   (T_DIM / SEG)        // 64

typedef float vfloat4 __attribute__((ext_vector_type(4)));

// ---- workspace layout (floats) ----
#define OFF_WT   0                                  // 512*192      = 98304
#define OFF_V    (OFF_WT + IN_D * 192)
#define OFF_K    (OFF_V  + NROWS * 64)              // becomes w=k*decay in place
#define OFF_Z    (OFF_K  + NROWS * 64)              // alpha logits -> log alpha in place
#define OFF_SEG  (OFF_Z  + NROWS * 64)              // 64*512
#define OFF_TOT  (OFF_SEG + NSEG * B_DIM * 64)      // 512
#define OFF_P    (OFF_TOT + B_DIM * 64)             // 64*8*4096 = 2097152

// K0: concat+transpose weights -> Wt[i][c], i<512, c<192
__global__ void k0_wt(const float* __restrict__ Wv, const float* __restrict__ Wk,
                      const float* __restrict__ Wa, float* __restrict__ Wt) {
    int idx = blockIdx.x * 256 + threadIdx.x;       // < 98304
    int i = idx / 192, c = idx % 192;
    float v;
    if (c < 64)       v = Wv[c * IN_D + i];
    else if (c < 128) v = Wk[(c - 64) * IN_D + i];
    else              v = Wa[(c - 128) * IN_D + i];
    Wt[i * 192 + c] = v;
}

// K1: projections, all-b128 LDS. 256 blocks x 256 thr; block = 32 rows, K-split-2.
// Thread (within K-half): rq=0..7 (4 rows), cq=0..15 (1 col-quad per matrix). 48 FMA / 4 b128 per kk.
__global__ __launch_bounds__(256) void k1_proj(
        const float* __restrict__ x, const float* __restrict__ Wt,
        const float* __restrict__ bv, const float* __restrict__ bk, const float* __restrict__ ba,
        float* __restrict__ V, float* __restrict__ Kb, float* __restrict__ Zb) {
    __shared__ float xs[2][32][32];     // [half][kk][row] 8 KB, transposed x
    __shared__ float wsm[2][32][192];   // [half][kk][col] 48 KB
    const int tid  = threadIdx.x;
    const int h    = tid >> 7;          // K half: 0 -> K[0:256), 1 -> K[256:512)
    const int t7   = tid & 127;
    const int rq   = t7 >> 4;           // row quad 0..7
    const int cq   = t7 & 15;           // col quad 0..15
    const int row0 = blockIdx.x * 32;

    float4 acc[4][3];
#pragma unroll
    for (int j = 0; j < 4; ++j)
#pragma unroll
        for (int m = 0; m < 3; ++m) acc[j][m] = make_float4(0.f, 0.f, 0.f, 0.f);

    for (int s = 0; s < 8; ++s) {       // K-slice of 32 per half
        // stage x transposed: 512 float4 loads -> scalar transpose writes (bank-clean)
#pragma unroll
        for (int q = 0; q < 2; ++q) {
            int idx = tid + q * 256;            // 0..511
            int hh = idx >> 8, r = idx & 31, f = (idx >> 5) & 7;
            float4 v4 = reinterpret_cast<const float4*>(x)[((row0 + r) * IN_D + hh * 256 + s * 32 + f * 4) >> 2];
            xs[hh][f * 4 + 0][r] = v4.x;
            xs[hh][f * 4 + 1][r] = v4.y;
            xs[hh][f * 4 + 2][r] = v4.z;
            xs[hh][f * 4 + 3][r] = v4.w;
        }
        // stage Wt slice: 3072 float4, direct b128 writes
#pragma unroll
        for (int q = 0; q < 12; ++q) {
            int idx = tid + q * 256;            // 0..3071
            int hh = idx / 1536;
            int rem = idx - hh * 1536;
            int kk = rem / 48;
            int f  = rem - kk * 48;
            float4 v4 = reinterpret_cast<const float4*>(Wt)[((hh * 256 + s * 32 + kk) * 192 + f * 4) >> 2];
            *reinterpret_cast<float4*>(&wsm[hh][kk][f * 4]) = v4;
        }
        __syncthreads();

#pragma unroll 4
        for (int kk = 0; kk < 32; ++kk) {
            float4 xv = *reinterpret_cast<const float4*>(&xs[h][kk][rq * 4]);
#pragma unroll
            for (int m = 0; m < 3; ++m) {
                float4 wq = *reinterpret_cast<const float4*>(&wsm[h][kk][m * 64 + cq * 4]);
#pragma unroll
                for (int j = 0; j < 4; ++j) {
                    float xx = (&xv.x)[j];
                    acc[j][m].x = fmaf(xx, wq.x, acc[j][m].x);
                    acc[j][m].y = fmaf(xx, wq.y, acc[j][m].y);
                    acc[j][m].z = fmaf(xx, wq.z, acc[j][m].z);
                    acc[j][m].w = fmaf(xx, wq.w, acc[j][m].w);
                }
            }
        }
        __syncthreads();
    }

    // cross-half reduce via LDS (reuse wsm; stride 52 floats to dodge bank conflicts)
    float* red = &wsm[0][0][0];
    if (h == 1) {
#pragma unroll
        for (int j = 0; j < 4; ++j)
#pragma unroll
            for (int m = 0; m < 3; ++m)
                *reinterpret_cast<float4*>(&red[t7 * 52 + (j * 3 + m) * 4]) = acc[j][m];
    }
    __syncthreads();
    if (h == 0) {
        float4 bv4 = *reinterpret_cast<const float4*>(&bv[cq * 4]);
        float4 bk4 = *reinterpret_cast<const float4*>(&bk[cq * 4]);
        float4 ba4 = *reinterpret_cast<const float4*>(&ba[cq * 4]);
#pragma unroll
        for (int j = 0; j < 4; ++j) {
            int row = row0 + rq * 4 + j;
#pragma unroll
            for (int m = 0; m < 3; ++m) {
                float4 o = *reinterpret_cast<const float4*>(&red[t7 * 52 + (j * 3 + m) * 4]);
                o.x += (&acc[j][m].x)[0]; // add own half
                o.x = acc[j][m].x + (&o.x)[0] - acc[j][m].x; // (kept simple below)
            }
            float4 o0 = *reinterpret_cast<const float4*>(&red[t7 * 52 + (j * 3 + 0) * 4]);
            float4 o1 = *reinterpret_cast<const float4*>(&red[t7 * 52 + (j * 3 + 1) * 4]);
            float4 o2 = *reinterpret_cast<const float4*>(&red[t7 * 52 + (j * 3 + 2) * 4]);
            float4 r0, r1, r2;
            r0.x = acc[j][0].x + o0.x + bv4.x; r0.y = acc[j][0].y + o0.y + bv4.y;
            r0.z = acc[j][0].z + o0.z + bv4.z; r0.w = acc[j][0].w + o0.w + bv4.w;
            r1.x = acc[j][1].x + o1.x + bk4.x; r1.y = acc[j][1].y + o1.y + bk4.y;
            r1.z = acc[j][1].z + o1.z + bk4.z; r1.w = acc[j][1].w + o1.w + bk4.w;
            r2.x = acc[j][2].x + o2.x + ba4.x; r2.y = acc[j][2].y + o2.y + ba4.y;
            r2.z = acc[j][2].z + o2.z + ba4.z; r2.w = acc[j][2].w + o2.w + ba4.w;
            *reinterpret_cast<float4*>(&V [row * 64 + cq * 4]) = r0;
            *reinterpret_cast<float4*>(&Kb[row * 64 + cq * 4]) = r1;
            *reinterpret_cast<float4*>(&Zb[row * 64 + cq * 4]) = r2;
        }
    }
}

// K2a: log(sigmoid) + segment sums. 512 blocks (b,s) x 64 thr. Z -> log alpha in place.
__global__ void k2a_logs(float* __restrict__ Z, float* __restrict__ seg) {
    int b = blockIdx.x & 7, s = blockIdx.x >> 3;
    int n = threadIdx.x;
    int base = b * 64 + n;
    float accv = 0.f;
#pragma unroll
    for (int i = 0; i < SEG; ++i) {
        int t = s * SEG + i;
        float z = Z[t * 512 + base];
        float a = 1.f / (1.f + expf(-z));
        float l = logf(fmaxf(a, EPSF));
        Z[t * 512 + base] = l;
        accv += l;
    }
    seg[s * 512 + base] = accv;
}

// K2b: exclusive scan of 64 segment sums per channel + totals. 1 block x 512 thr.
__global__ void k2b_scan(float* __restrict__ seg, float* __restrict__ tot) {
    int i = threadIdx.x;
    float vals[NSEG];
#pragma unroll
    for (int s = 0; s < NSEG; ++s) vals[s] = seg[s * 512 + i];
    float run = 0.f;
#pragma unroll
    for (int s = 0; s < NSEG; ++s) { seg[s * 512 + i] = run; run += vals[s]; }
    tot[i] = run;
}

// K2c: w[t] = k[t]*exp(logcum[t])/(exp(total)+eps). 512 blocks x 64 thr. Kb in place.
__global__ void k2c_w(const float* __restrict__ Z, const float* __restrict__ seg,
                      const float* __restrict__ tot, float* __restrict__ Kb) {
    int b = blockIdx.x & 7, s = blockIdx.x >> 3;
    int n = threadIdx.x;
    int base = b * 64 + n;
    float run = seg[s * 512 + base];
    float invden = 1.f / (expf(tot[base]) + EPSF);
#pragma unroll
    for (int i = 0; i < SEG; ++i) {
        int t = s * SEG + i;
        run += Z[t * 512 + base];
        Kb[t * 512 + base] *= expf(run) * invden;
    }
}

// K3: per-chunk partial outer sums P[c][b][d][n]. 512 blocks (b,c) x 256 thr.
__global__ __launch_bounds__(256) void k3_partial(const float* __restrict__ V,
                                                  const float* __restrict__ W,
                                                  float* __restrict__ P) {
    __shared__ float vs[CHUNK * 64];
    __shared__ float wsh[CHUNK * 64];
    int b = blockIdx.x & 7, cch = blockIdx.x >> 3;
    int tid = threadIdx.x;
    int dg = tid >> 4, n4 = tid & 15;
    {
        int il = tid >> 4, f = tid & 15;
        int row = (cch * CHUNK + il) * 8 + b;
        reinterpret_cast<float4*>(vs)[il * 16 + f]  = reinterpret_cast<const float4*>(V)[row * 16 + f];
        reinterpret_cast<float4*>(wsh)[il * 16 + f] = reinterpret_cast<const float4*>(W)[row * 16 + f];
    }
    __syncthreads();
    float4 acc[4];
#pragma unroll
    for (int q = 0; q < 4; ++q) acc[q] = make_float4(0.f, 0.f, 0.f, 0.f);

#pragma unroll
    for (int i = 0; i < CHUNK; ++i) {
        float4 wv = reinterpret_cast<const float4*>(wsh)[i * 16 + n4];
#pragma unroll
        for (int q = 0; q < 4; ++q) {
            float vd = vs[i * 64 + dg + 16 * q];
            acc[q].x = fmaf(vd, wv.x, acc[q].x);
            acc[q].y = fmaf(vd, wv.y, acc[q].y);
            acc[q].z = fmaf(vd, wv.z, acc[q].z);
            acc[q].w = fmaf(vd, wv.w, acc[q].w);
        }
    }
    float* Pp = P + (cch * 8 + b) * 4096;
#pragma unroll
    for (int q = 0; q < 4; ++q)
        *reinterpret_cast<float4*>(Pp + (dg + 16 * q) * 64 + 4 * n4) = acc[q];
}

// K4: exclusive prefix over 64 chunks, in place. 128 blocks x 256 thr.
__global__ __launch_bounds__(256) void k4_prefix(float* __restrict__ P) {
    int gid = blockIdx.x * 256 + threadIdx.x;   // < 32768
    int b = gid >> 12, dn = gid & 4095;
    float run = 0.f;
#pragma unroll
    for (int c = 0; c < NCHUNK; ++c) {
        float v = P[(c * 8 + b) * 4096 + dn];
        P[(c * 8 + b) * 4096 + dn] = run;
        run += v;
    }
}

// K5: main cumsum + streaming store (134 MB). 512 blocks (b,c) x 256 thr.
__global__ __launch_bounds__(256) void k5_main(const float* __restrict__ V,
                                               const float* __restrict__ W,
                                               const float* __restrict__ P,
                                               float* __restrict__ S) {
    __shared__ float vs[CHUNK * 64];
    __shared__ float wsh[CHUNK * 64];
    int b = blockIdx.x & 7, cch = blockIdx.x >> 3;
    int tid = threadIdx.x;
    int dg = tid >> 4, n4 = tid & 15;
    {
        int il = tid >> 4, f = tid & 15;
        int row = (cch * CHUNK + il) * 8 + b;
        reinterpret_cast<float4*>(vs)[il * 16 + f]  = reinterpret_cast<const float4*>(V)[row * 16 + f];
        reinterpret_cast<float4*>(wsh)[il * 16 + f] = reinterpret_cast<const float4*>(W)[row * 16 + f];
    }
    vfloat4 acc[4];
    const float* Pp = P + (cch * 8 + b) * 4096;
#pragma unroll
    for (int q = 0; q < 4; ++q)
        acc[q] = *reinterpret_cast<const vfloat4*>(Pp + (dg + 16 * q) * 64 + 4 * n4);
    __syncthreads();

#pragma unroll
    for (int i = 0; i < CHUNK; ++i) {
        float4 wv = reinterpret_cast<const float4*>(wsh)[i * 16 + n4];
        int t = cch * CHUNK + i;
        float* Sb = S + (size_t)t * 32768 + b * 4096;
#pragma unroll
        for (int q = 0; q < 4; ++q) {
            float vd = vs[i * 64 + dg + 16 * q];
            acc[q].x = fmaf(vd, wv.x, acc[q].x);
            acc[q].y = fmaf(vd, wv.y, acc[q].y);
            acc[q].z = fmaf(vd, wv.z, acc[q].z);
            acc[q].w = fmaf(vd, wv.w, acc[q].w);
            __builtin_nontemporal_store(acc[q],
                reinterpret_cast<vfloat4*>(Sb + (dg + 16 * q) * 64 + 4 * n4));
        }
    }
}

extern "C" void kernel_launch(void* const* d_in, const int* in_sizes, int n_in,
                              void* d_out, int out_size, void* d_ws, size_t ws_size,
                              hipStream_t stream) {
    const float* x  = (const float*)d_in[0];
    const float* Wv = (const float*)d_in[1];
    const float* bv = (const float*)d_in[2];
    const float* Wk = (const float*)d_in[3];
    const float* bk = (const float*)d_in[4];
    const float* Wa = (const float*)d_in[5];
    const float* ba = (const float*)d_in[6];
    float* S  = (float*)d_out;
    float* ws = (float*)d_ws;

    float* Wt  = ws + OFF_WT;
    float* V   = ws + OFF_V;
    float* Kb  = ws + OFF_K;
    float* Zb  = ws + OFF_Z;
    float* seg = ws + OFF_SEG;
    float* tot = ws + OFF_TOT;
    float* P   = ws + OFF_P;

    k0_wt     <<<384, 256, 0, stream>>>(Wv, Wk, Wa, Wt);
    k1_proj   <<<256, 256, 0, stream>>>(x, Wt, bv, bk, ba, V, Kb, Zb);
    k2a_logs  <<<512,  64, 0, stream>>>(Zb, seg);
    k2b_scan  <<<  1, 512, 0, stream>>>(seg, tot);
    k2c_w     <<<512,  64, 0, stream>>>(Zb, seg, tot, Kb);
    k3_partial<<<512, 256, 0, stream>>>(V, Kb, P);
    k4_prefix <<<128, 256, 0, stream>>>(P);
    k5_main   <<<512, 256, 0, stream>>>(V, Kb, P, S);
}